// Round 1
// 529.367 us; speedup vs baseline: 1.0387x; 1.0387x over previous
//
#include <hip/hip_runtime.h>
#include <math.h>

#define CIN  32
#define COUT 64
#define KVOL 27
#define EPSF 1e-5f

typedef __attribute__((ext_vector_type(8))) short          short8;
typedef __attribute__((ext_vector_type(8))) unsigned short u16x8;
typedef __attribute__((ext_vector_type(4))) float          float4v;

__device__ __forceinline__ float eluf(float x) { return x > 0.f ? x : expm1f(x); }

// f32 -> bf16 round-to-nearest-even
__device__ __forceinline__ unsigned short f2bf(float x) {
    unsigned u = __float_as_uint(x);
    unsigned r = (u + 0x7FFFu + ((u >> 16) & 1u)) >> 16;
    return (unsigned short)r;
}
__device__ __forceinline__ unsigned pk2bf(float lo, float hi) {
    return (unsigned)f2bf(lo) | ((unsigned)f2bf(hi) << 16);
}
__device__ __forceinline__ float bf2f(unsigned short h) {
    return __uint_as_float(((unsigned)h) << 16);
}

// ---------------------------------------------------------------------------
// Weight prep: W1/W2 [k][i][c] f32 -> Wt [k][c][i] bf16 (B-frags contiguous),
// block 54: Wd [i][c] f32 -> Wdt [c][i] bf16.
// ---------------------------------------------------------------------------
__global__ void cvt_w_kernel(const float* __restrict__ W1, const float* __restrict__ W2,
                             const float* __restrict__ Wd,
                             unsigned short* __restrict__ Wt1, unsigned short* __restrict__ Wt2,
                             unsigned short* __restrict__ Wdt)
{
    int b = blockIdx.x;  // 0..54
    int t = threadIdx.x;
    if (b == 54) {
        for (int e = t; e < CIN * COUT; e += 256) {
            int i = e >> 6, c = e & 63;
            Wdt[c * CIN + i] = f2bf(Wd[e]);
        }
        return;
    }
    const float* W = (b < 27) ? W1 : W2;
    unsigned short* Wt = (b < 27) ? Wt1 : Wt2;
    int k = (b < 27) ? b : b - 27;
    const float* src = W + (size_t)k * (COUT * COUT);
    unsigned short* dst = Wt + (size_t)k * (COUT * COUT);
    for (int e = t; e < COUT * COUT; e += 256) {
        int i = e >> 6, c = e & 63;
        dst[c * COUT + i] = f2bf(src[e]);
    }
}

// ---------------------------------------------------------------------------
// Transposed streaming down-conv: t^T = Wd^T @ feats^T, zero LDS in hot loop.
// ---------------------------------------------------------------------------
__global__ __launch_bounds__(256) void gemm_t_kernel(
    const float* __restrict__ feats, const unsigned short* __restrict__ Wdt,
    int N, unsigned short* __restrict__ t_bf, float* __restrict__ red0)
{
    __shared__ float red_s[64];
    __shared__ float red_q[64];
    int t = threadIdx.x;
    if (t < 64) { red_s[t] = 0.f; red_q[t] = 0.f; }
    __syncthreads();

    int w = t >> 6, lane = t & 63, l15 = lane & 15, quad = lane >> 4;

    // hoist A-frags: aw[mt] = Wd^T rows 16mt+l15, k = quad*8..+7
    short8 aw[4];
    #pragma unroll
    for (int mt = 0; mt < 4; ++mt)
        aw[mt] = *(const short8*)(Wdt + (size_t)(16 * mt + l15) * CIN + quad * 8);

    float s1[16], sq[16];
    #pragma unroll
    for (int e = 0; e < 16; ++e) { s1[e] = 0.f; sq[e] = 0.f; }

    int numTiles = (N + 15) >> 4;
    int stride = gridDim.x * 4;
    int tile = blockIdx.x * 4 + w;

    float4 c0 = make_float4(0.f, 0.f, 0.f, 0.f), c1 = c0;
    {
        int pt = tile * 16 + l15;
        if (tile < numTiles && pt < N) {
            const float4* s = (const float4*)(feats + (size_t)pt * CIN + quad * 8);
            c0 = s[0]; c1 = s[1];
        }
    }

    while (tile < numTiles) {
        // prefetch next tile
        int nt = tile + stride;
        float4 n0 = make_float4(0.f, 0.f, 0.f, 0.f), n1 = n0;
        {
            int npt = nt * 16 + l15;
            if (nt < numTiles && npt < N) {
                const float4* s = (const float4*)(feats + (size_t)npt * CIN + quad * 8);
                n0 = s[0]; n1 = s[1];
            }
        }
        // convert current B-frag (feats[pt][quad*8..+7] -> 8 bf16)
        union { short8 v; unsigned u[4]; } b;
        b.u[0] = pk2bf(c0.x, c0.y);
        b.u[1] = pk2bf(c0.z, c0.w);
        b.u[2] = pk2bf(c1.x, c1.y);
        b.u[3] = pk2bf(c1.z, c1.w);

        float4v acc[4];
        #pragma unroll
        for (int mt = 0; mt < 4; ++mt)
            acc[mt] = __builtin_amdgcn_mfma_f32_16x16x32_bf16(
                aw[mt], b.v, (float4v){0.f, 0.f, 0.f, 0.f}, 0, 0, 0);

        int pt = tile * 16 + l15;
        if (pt < N) {
            #pragma unroll
            for (int mt = 0; mt < 4; ++mt) {
                uint2 o;
                o.x = pk2bf(acc[mt][0], acc[mt][1]);
                o.y = pk2bf(acc[mt][2], acc[mt][3]);
                *(uint2*)(t_bf + (size_t)pt * COUT + mt * 16 + quad * 4) = o;
            }
        }
        // stats (padded lanes contribute exact zeros)
        #pragma unroll
        for (int mt = 0; mt < 4; ++mt)
            #pragma unroll
            for (int e = 0; e < 4; ++e) {
                float v = acc[mt][e];
                s1[mt * 4 + e] += v; sq[mt * 4 + e] += v * v;
            }
        c0 = n0; c1 = n1;
        tile = nt;
    }

    // reduce stats: butterfly over the 16 point-lanes, then LDS, then global
    #pragma unroll
    for (int m = 1; m <= 8; m <<= 1) {
        #pragma unroll
        for (int e = 0; e < 16; ++e) {
            s1[e] += __shfl_xor(s1[e], m);
            sq[e] += __shfl_xor(sq[e], m);
        }
    }
    if (l15 == 0) {
        #pragma unroll
        for (int e = 0; e < 16; ++e) {
            int ch = (e >> 2) * 16 + quad * 4 + (e & 3);
            atomicAdd(&red_s[ch], s1[e]);
            atomicAdd(&red_q[ch], sq[e]);
        }
    }
    __syncthreads();
    float* dst = red0 + (size_t)(blockIdx.x & 3) * 128;
    if (t < 64)       atomicAdd(&dst[t], red_s[t]);
    else if (t < 128) atomicAdd(&dst[t], red_q[t - 64]);
}

// BN finalize from 4-way-spread sum/sumsq (for BN0)
__global__ void fin0_kernel(const float* __restrict__ red, const float* __restrict__ g,
                            const float* __restrict__ b, float* __restrict__ scale,
                            float* __restrict__ shift, int cnt)
{
    int c = threadIdx.x;  // 64
    float s = 0.f, q = 0.f;
    #pragma unroll
    for (int i = 0; i < 4; ++i) { s += red[i * 128 + c]; q += red[i * 128 + 64 + c]; }
    float m = s / (float)cnt;
    float var = q / (float)cnt - m * m;
    float sc = g[c] / sqrtf(var + EPSF);
    scale[c] = sc;
    shift[c] = b[c] - m * sc;
}

// ---------------------------------------------------------------------------
// Bucket build: pooling cell = 2x2x4 = 16 voxels max -> fixed capacity 16.
// ---------------------------------------------------------------------------
__global__ void bucket_kernel(const int* __restrict__ pool_seg,
                              int* __restrict__ cnt, int* __restrict__ bucket, int N)
{
    int j = blockIdx.x * 256 + threadIdx.x;
    if (j < N) {
        int s = pool_seg[j];
        int pos = atomicAdd(&cnt[s], 1);
        bucket[(size_t)s * 16 + pos] = j;
    }
}

// ---------------------------------------------------------------------------
// Gather-only pool: thread = (segment, 4 channels).
// ---------------------------------------------------------------------------
__global__ __launch_bounds__(256) void pool_max_kernel(
    const unsigned short* __restrict__ t_bf,
    const int* __restrict__ cnt, const int* __restrict__ bucket,
    const float* __restrict__ scale0, const float* __restrict__ shift0,
    unsigned short* __restrict__ down_bf, int M)
{
    int id = blockIdx.x * 256 + threadIdx.x;
    int s = id >> 4, cg = id & 15;
    if (s >= M) return;
    int n = cnt[s];
    const int4* bk4 = (const int4*)(bucket + (size_t)s * 16);
    float4 mx = make_float4(-INFINITY, -INFINITY, -INFINITY, -INFINITY);
    float4 mn = make_float4( INFINITY,  INFINITY,  INFINITY,  INFINITY);
    #pragma unroll
    for (int ch = 0; ch < 4; ++ch) {
        if (ch * 4 >= n) break;
        int4 b4 = bk4[ch];
        #pragma unroll
        for (int e = 0; e < 4; ++e) {
            int p = ch * 4 + e;
            if (p < n) {
                int idx = (e == 0) ? b4.x : (e == 1) ? b4.y : (e == 2) ? b4.z : b4.w;
                ushort4 v = *(const ushort4*)(t_bf + (size_t)idx * COUT + cg * 4);
                float f0 = bf2f(v.x), f1 = bf2f(v.y), f2 = bf2f(v.z), f3 = bf2f(v.w);
                mx.x = fmaxf(mx.x, f0); mn.x = fminf(mn.x, f0);
                mx.y = fmaxf(mx.y, f1); mn.y = fminf(mn.y, f1);
                mx.z = fmaxf(mx.z, f2); mn.z = fminf(mn.z, f2);
                mx.w = fmaxf(mx.w, f3); mn.w = fminf(mn.w, f3);
            }
        }
    }
    int c0 = cg * 4;
    float4 sc = *(const float4*)(scale0 + c0);
    float4 sh = *(const float4*)(shift0 + c0);
    ushort4 o;
    o.x = f2bf(eluf(sc.x * (sc.x >= 0.f ? mx.x : mn.x) + sh.x));
    o.y = f2bf(eluf(sc.y * (sc.y >= 0.f ? mx.y : mn.y) + sh.y));
    o.z = f2bf(eluf(sc.z * (sc.z >= 0.f ? mx.z : mn.z) + sh.z));
    o.w = f2bf(eluf(sc.w * (sc.w >= 0.f ? mx.w : mn.w) + sh.w));
    *(ushort4*)(down_bf + (size_t)s * COUT + c0) = o;
}

// invert (k, pairlist) maps into nbrT[k][M] (transposed for coalesced conv reads)
__global__ void nbr_kernel(const int* __restrict__ conv_out, const int* __restrict__ conv_in,
                           int* __restrict__ nbrT, int L, int M)
{
    int k = blockIdx.y;
    int idx = blockIdx.x * 256 + threadIdx.x;
    if (idx < L) {
        int e = k * L + idx;
        int j = conv_out[e];
        if (j < M) nbrT[(size_t)k * M + j] = conv_in[e];
    }
}

// o1t = bf16( ELU(scale1*o1 + shift1) )  -- conv2's A-matrix. float4 vectorized.
__global__ void bn_elu_cvt_kernel(const float* __restrict__ o1,
                                  const float* __restrict__ scale,
                                  const float* __restrict__ shift,
                                  unsigned short* __restrict__ o1t, int n4)
{
    int i = blockIdx.x * 256 + threadIdx.x;
    if (i < n4) {
        float4 v = ((const float4*)o1)[i];
        int c0 = (i & 15) * 4;
        float4 sc = *(const float4*)(scale + c0);
        float4 sh = *(const float4*)(shift + c0);
        ushort4 o;
        o.x = f2bf(eluf(v.x * sc.x + sh.x));
        o.y = f2bf(eluf(v.y * sc.y + sh.y));
        o.z = f2bf(eluf(v.z * sc.z + sh.z));
        o.w = f2bf(eluf(v.w * sc.w + sh.w));
        ((ushort4*)o1t)[i] = o;
    }
}

// ---------------------------------------------------------------------------
// MFMA implicit-GEMM sparse conv. Block = 128 rows x 64 cols, 4 waves.
// v2: LDS double-buffered, ONE barrier per k-offset. Next-offset A rows (gather)
// and W tile are prefetched into registers at the top of iteration k and
// ds_written to the back buffer after the MFMAs -> global-load latency hides
// under the compute phase instead of sitting between two barriers.
// XOR swizzle (16B slot ^= row&7) on both ds_write and ds_read sides gives an
// even 8-lane/bank-group distribution (conflict-minimal b128 access).
// Fused BN stats epilogue.
// ---------------------------------------------------------------------------
__global__ __launch_bounds__(256) void conv_mfma_kernel(
    const unsigned short* __restrict__ in, const unsigned short* __restrict__ Wt,
    const int* __restrict__ nbrT, int M,
    float* __restrict__ out, float* __restrict__ red)
{
    __shared__ __align__(16) unsigned short A_lds[2][128 * 64];  // 32 KB
    __shared__ __align__(16) unsigned short W_lds[2][64 * 64];   // 16 KB
    __shared__ float red_s[64];
    __shared__ float red_q[64];
    int t = threadIdx.x;
    int base = blockIdx.x * 128;
    int w = t >> 6, lane = t & 63, l15 = lane & 15, quad = lane >> 4;

    if (t < 64) { red_s[t] = 0.f; red_q[t] = 0.f; }

    float4v acc[2][4];
    #pragma unroll
    for (int s = 0; s < 2; ++s)
        #pragma unroll
        for (int n = 0; n < 4; ++n)
            acc[s][n] = (float4v){0.f, 0.f, 0.f, 0.f};

    int ar = t >> 1, ah = t & 1;   // A staging: row, 64B-half (4x16B chunks)
    int gj = base + ar;
    int wc = t >> 2, wq = t & 3;   // W staging: row, 32B-chunk-pair
    int arx = ar & 7;              // A row swizzle key
    int wcx = wc & 7;              // W row swizzle key

    const u16x8 z8 = (u16x8){0, 0, 0, 0, 0, 0, 0, 0};

    // ---- prologue: stage k=0 into buf0, prefetch idx for k=1 ----
    {
        int idx0 = (gj < M) ? nbrT[gj] : -1;
        u16x8 a0 = z8, a1 = z8, a2 = z8, a3 = z8;
        if (idx0 >= 0) {
            const u16x8* src = (const u16x8*)(in + (size_t)idx0 * COUT);
            a0 = src[ah * 4 + 0]; a1 = src[ah * 4 + 1];
            a2 = src[ah * 4 + 2]; a3 = src[ah * 4 + 3];
        }
        const u16x8* ws = (const u16x8*)(Wt + (size_t)wc * COUT);
        u16x8 w0 = ws[wq * 2], w1 = ws[wq * 2 + 1];

        unsigned short* Ab = A_lds[0];
        *(u16x8*)(Ab + ar * 64 + ((ah * 4 + 0) ^ arx) * 8) = a0;
        *(u16x8*)(Ab + ar * 64 + ((ah * 4 + 1) ^ arx) * 8) = a1;
        *(u16x8*)(Ab + ar * 64 + ((ah * 4 + 2) ^ arx) * 8) = a2;
        *(u16x8*)(Ab + ar * 64 + ((ah * 4 + 3) ^ arx) * 8) = a3;
        unsigned short* Wb = W_lds[0];
        *(u16x8*)(Wb + wc * 64 + ((wq * 2 + 0) ^ wcx) * 8) = w0;
        *(u16x8*)(Wb + wc * 64 + ((wq * 2 + 1) ^ wcx) * 8) = w1;
    }
    int idxN = (gj < M) ? nbrT[(size_t)M + gj] : -1;  // k=1
    __syncthreads();

    for (int k = 0; k < KVOL; ++k) {
        int cur = k & 1;
        bool pf = (k + 1 < KVOL);

        // ---- issue prefetch for k+1 (regs) ----
        u16x8 na0 = z8, na1 = z8, na2 = z8, na3 = z8, nw0 = z8, nw1 = z8;
        if (pf) {
            if (idxN >= 0) {
                const u16x8* src = (const u16x8*)(in + (size_t)idxN * COUT);
                na0 = src[ah * 4 + 0]; na1 = src[ah * 4 + 1];
                na2 = src[ah * 4 + 2]; na3 = src[ah * 4 + 3];
            }
            const u16x8* ws = (const u16x8*)(Wt + (size_t)(k + 1) * (COUT * COUT) + (size_t)wc * COUT);
            nw0 = ws[wq * 2]; nw1 = ws[wq * 2 + 1];
            idxN = (k + 2 < KVOL && gj < M) ? nbrT[(size_t)(k + 2) * M + gj] : -1;
        }

        // ---- compute on buf[cur] ----
        const unsigned short* Ab = A_lds[cur];
        const unsigned short* Wb = W_lds[cur];
        #pragma unroll
        for (int kk = 0; kk < 64; kk += 32) {
            int slb = quad + (kk >> 3);  // 16B slot index 0..7
            int r0 = 32 * w + l15;
            short8 a0 = *(const short8*)(Ab + r0 * 64 + ((slb ^ (r0 & 7)) * 8));
            int r1 = r0 + 16;
            short8 a1 = *(const short8*)(Ab + r1 * 64 + ((slb ^ (r1 & 7)) * 8));
            #pragma unroll
            for (int n = 0; n < 4; ++n) {
                int rb = 16 * n + l15;
                short8 b = *(const short8*)(Wb + rb * 64 + ((slb ^ (rb & 7)) * 8));
                acc[0][n] = __builtin_amdgcn_mfma_f32_16x16x32_bf16(a0, b, acc[0][n], 0, 0, 0);
                acc[1][n] = __builtin_amdgcn_mfma_f32_16x16x32_bf16(a1, b, acc[1][n], 0, 0, 0);
            }
        }

        // ---- drain prefetch into back buffer ----
        if (pf) {
            unsigned short* An = A_lds[cur ^ 1];
            *(u16x8*)(An + ar * 64 + ((ah * 4 + 0) ^ arx) * 8) = na0;
            *(u16x8*)(An + ar * 64 + ((ah * 4 + 1) ^ arx) * 8) = na1;
            *(u16x8*)(An + ar * 64 + ((ah * 4 + 2) ^ arx) * 8) = na2;
            *(u16x8*)(An + ar * 64 + ((ah * 4 + 3) ^ arx) * 8) = na3;
            unsigned short* Wn = W_lds[cur ^ 1];
            *(u16x8*)(Wn + wc * 64 + ((wq * 2 + 0) ^ wcx) * 8) = nw0;
            *(u16x8*)(Wn + wc * 64 + ((wq * 2 + 1) ^ wcx) * 8) = nw1;
        }
        __syncthreads();
    }

    // stores (C/D layout: col=lane&15, row=quad*4+reg)
    #pragma unroll
    for (int s = 0; s < 2; ++s) {
        int row = base + 32 * w + 16 * s + quad * 4;
        #pragma unroll
        for (int n = 0; n < 4; ++n) {
            int c = 16 * n + l15;
            #pragma unroll
            for (int e = 0; e < 4; ++e)
                if (row + e < M) out[(size_t)(row + e) * COUT + c] = acc[s][n][e];
        }
    }
    // fused BN stats (rows >= M are exact zeros)
    #pragma unroll
    for (int n = 0; n < 4; ++n) {
        float s1 = 0.f, sq = 0.f;
        #pragma unroll
        for (int s = 0; s < 2; ++s)
            #pragma unroll
            for (int e = 0; e < 4; ++e) { float v = acc[s][n][e]; s1 += v; sq += v * v; }
        s1 += __shfl_xor(s1, 16); sq += __shfl_xor(sq, 16);
        s1 += __shfl_xor(s1, 32); sq += __shfl_xor(sq, 32);
        if (quad == 0) {
            atomicAdd(&red_s[16 * n + l15], s1);
            atomicAdd(&red_q[16 * n + l15], sq);
        }
    }
    __syncthreads();
    if (t < 64)       atomicAdd(&red[t], red_s[t]);
    else if (t < 128) atomicAdd(&red[t], red_q[t - 64]);
}

// BN finalize from sum/sumsq: scale = g/sqrt(var+eps), shift = b - mean*scale
__global__ void finC_kernel(const float* __restrict__ red, const float* __restrict__ g,
                            const float* __restrict__ b, float* __restrict__ scale,
                            float* __restrict__ shift, int M)
{
    int c = threadIdx.x;  // 64
    float m = red[c] / (float)M;
    float var = red[64 + c] / (float)M - m * m;
    float sc = g[c] / sqrtf(var + EPSF);
    scale[c] = sc;
    shift[c] = b[c] - m * sc;
}

// out = elu( elu(scale2*raw + shift2) + down )  -- float4 vectorized
__global__ void final_kernel(float* __restrict__ out, const unsigned short* __restrict__ down_bf,
                             const float* __restrict__ scale2, const float* __restrict__ shift2,
                             int n4)
{
    int i = blockIdx.x * 256 + threadIdx.x;
    if (i < n4) {
        float4 v = ((const float4*)out)[i];
        ushort4 d = ((const ushort4*)down_bf)[i];
        int c0 = (i & 15) * 4;
        float4 sc = *(const float4*)(scale2 + c0);
        float4 sh = *(const float4*)(shift2 + c0);
        v.x = eluf(eluf(v.x * sc.x + sh.x) + bf2f(d.x));
        v.y = eluf(eluf(v.y * sc.y + sh.y) + bf2f(d.y));
        v.z = eluf(eluf(v.z * sc.z + sh.z) + bf2f(d.z));
        v.w = eluf(eluf(v.w * sc.w + sh.w) + bf2f(d.w));
        ((float4*)out)[i] = v;
    }
}

extern "C" void kernel_launch(void* const* d_in, const int* in_sizes, int n_in,
                              void* d_out, int out_size, void* d_ws, size_t ws_size,
                              hipStream_t stream)
{
    (void)n_in; (void)ws_size;
    const float* feats    = (const float*)d_in[0];
    const float* Wd       = (const float*)d_in[1];
    const float* g0       = (const float*)d_in[2];
    const float* b0       = (const float*)d_in[3];
    const float* W1       = (const float*)d_in[4];
    const float* g1       = (const float*)d_in[5];
    const float* b1       = (const float*)d_in[6];
    const float* W2       = (const float*)d_in[7];
    const float* g2       = (const float*)d_in[8];
    const float* b2       = (const float*)d_in[9];
    const int*   pool_seg = (const int*)d_in[10];
    const int*   conv_in  = (const int*)d_in[11];
    const int*   conv_out = (const int*)d_in[12];

    int N = in_sizes[0] / CIN;
    int M = out_size / COUT;
    int L = in_sizes[11] / KVOL;

    char* ws = (char*)d_ws;
    size_t off = 0;
    auto alloc = [&](size_t bytes) -> void* {
        void* p = ws + off;
        off = (off + bytes + 255) & ~(size_t)255;
        return p;
    };
    float*          o1      = (float*)alloc((size_t)M * COUT * 4);
    unsigned short* down_bf = (unsigned short*)alloc((size_t)M * COUT * 2);
    unsigned short* o1t     = (unsigned short*)alloc((size_t)M * COUT * 2);
    unsigned short* t_bf    = (unsigned short*)alloc((size_t)N * COUT * 2);
    int*            nbrT    = (int*)alloc((size_t)KVOL * M * 4);
    unsigned short* Wt1     = (unsigned short*)alloc((size_t)KVOL * COUT * COUT * 2);
    unsigned short* Wt2     = (unsigned short*)alloc((size_t)KVOL * COUT * COUT * 2);
    unsigned short* Wdt     = (unsigned short*)alloc((size_t)CIN * COUT * 2);
    int*            cnt     = (int*)alloc((size_t)M * 4);
    int*            bucket  = (int*)alloc((size_t)M * 16 * 4);
    float* red  = (float*)alloc((size_t)768 * 4);
    float* red0 = red, *red1 = red + 512, *red2 = red + 640;
    float* sreg = (float*)alloc((size_t)6 * 64 * 4);
    float* scale0 = sreg, *shift0 = sreg + 64;
    float* scale1 = sreg + 128, *shift1 = sreg + 192;
    float* scale2 = sreg + 256, *shift2 = sreg + 320;

    hipMemsetAsync(nbrT, 0xFF, (size_t)KVOL * M * 4, stream);  // -1 = missing neighbor
    hipMemsetAsync(cnt, 0, (size_t)M * 4, stream);             // bucket counters
    hipMemsetAsync(red, 0, (size_t)768 * 4, stream);           // stat accumulators

    cvt_w_kernel<<<55, 256, 0, stream>>>(W1, W2, Wd, Wt1, Wt2, Wdt);
    gemm_t_kernel<<<1024, 256, 0, stream>>>(feats, Wdt, N, t_bf, red0);
    fin0_kernel<<<1, 64, 0, stream>>>(red0, g0, b0, scale0, shift0, N);
    bucket_kernel<<<(N + 255) / 256, 256, 0, stream>>>(pool_seg, cnt, bucket, N);
    pool_max_kernel<<<(M * 16 + 255) / 256, 256, 0, stream>>>(
        t_bf, cnt, bucket, scale0, shift0, down_bf, M);
    dim3 gn((L + 255) / 256, KVOL);
    nbr_kernel<<<gn, 256, 0, stream>>>(conv_out, conv_in, nbrT, L, M);

    int cblocks = (M + 127) / 128;
    conv_mfma_kernel<<<cblocks, 256, 0, stream>>>(down_bf, Wt1, nbrT, M, o1, red1);
    finC_kernel<<<1, 64, 0, stream>>>(red1, g1, b1, scale1, shift1, M);
    int n4 = (M * COUT) / 4;
    bn_elu_cvt_kernel<<<(n4 + 255) / 256, 256, 0, stream>>>(o1, scale1, shift1, o1t, n4);
    conv_mfma_kernel<<<cblocks, 256, 0, stream>>>(o1t, Wt2, nbrT, M, (float*)d_out, red2);
    finC_kernel<<<1, 64, 0, stream>>>(red2, g2, b2, scale2, shift2, M);
    final_kernel<<<(n4 + 255) / 256, 256, 0, stream>>>(
        (float*)d_out, down_bf, scale2, shift2, n4);
}

// Round 2
// 491.301 us; speedup vs baseline: 1.1192x; 1.0775x over previous
//
#include <hip/hip_runtime.h>
#include <math.h>

#define CIN  32
#define COUT 64
#define KVOL 27
#define EPSF 1e-5f

typedef __attribute__((ext_vector_type(8))) short          short8;
typedef __attribute__((ext_vector_type(8))) unsigned short u16x8;
typedef __attribute__((ext_vector_type(4))) float          float4v;

__device__ __forceinline__ float eluf(float x) { return x > 0.f ? x : expm1f(x); }

// f32 -> bf16 round-to-nearest-even
__device__ __forceinline__ unsigned short f2bf(float x) {
    unsigned u = __float_as_uint(x);
    unsigned r = (u + 0x7FFFu + ((u >> 16) & 1u)) >> 16;
    return (unsigned short)r;
}
__device__ __forceinline__ unsigned pk2bf(float lo, float hi) {
    return (unsigned)f2bf(lo) | ((unsigned)f2bf(hi) << 16);
}
__device__ __forceinline__ float bf2f(unsigned short h) {
    return __uint_as_float(((unsigned)h) << 16);
}

// ---------------------------------------------------------------------------
// Weight prep: W1/W2 [k][i][c] f32 -> Wt [k][c][i] bf16 (B-frags contiguous),
// block 54: Wd [i][c] f32 -> Wdt [c][i] bf16.
// ---------------------------------------------------------------------------
__global__ void cvt_w_kernel(const float* __restrict__ W1, const float* __restrict__ W2,
                             const float* __restrict__ Wd,
                             unsigned short* __restrict__ Wt1, unsigned short* __restrict__ Wt2,
                             unsigned short* __restrict__ Wdt)
{
    int b = blockIdx.x;  // 0..54
    int t = threadIdx.x;
    if (b == 54) {
        for (int e = t; e < CIN * COUT; e += 256) {
            int i = e >> 6, c = e & 63;
            Wdt[c * CIN + i] = f2bf(Wd[e]);
        }
        return;
    }
    const float* W = (b < 27) ? W1 : W2;
    unsigned short* Wt = (b < 27) ? Wt1 : Wt2;
    int k = (b < 27) ? b : b - 27;
    const float* src = W + (size_t)k * (COUT * COUT);
    unsigned short* dst = Wt + (size_t)k * (COUT * COUT);
    for (int e = t; e < COUT * COUT; e += 256) {
        int i = e >> 6, c = e & 63;
        dst[c * COUT + i] = f2bf(src[e]);
    }
}

// ---------------------------------------------------------------------------
// Transposed streaming down-conv: t^T = Wd^T @ feats^T, zero LDS in hot loop.
// ---------------------------------------------------------------------------
__global__ __launch_bounds__(256) void gemm_t_kernel(
    const float* __restrict__ feats, const unsigned short* __restrict__ Wdt,
    int N, unsigned short* __restrict__ t_bf, float* __restrict__ red0)
{
    __shared__ float red_s[64];
    __shared__ float red_q[64];
    int t = threadIdx.x;
    if (t < 64) { red_s[t] = 0.f; red_q[t] = 0.f; }
    __syncthreads();

    int w = t >> 6, lane = t & 63, l15 = lane & 15, quad = lane >> 4;

    // hoist A-frags: aw[mt] = Wd^T rows 16mt+l15, k = quad*8..+7
    short8 aw[4];
    #pragma unroll
    for (int mt = 0; mt < 4; ++mt)
        aw[mt] = *(const short8*)(Wdt + (size_t)(16 * mt + l15) * CIN + quad * 8);

    float s1[16], sq[16];
    #pragma unroll
    for (int e = 0; e < 16; ++e) { s1[e] = 0.f; sq[e] = 0.f; }

    int numTiles = (N + 15) >> 4;
    int stride = gridDim.x * 4;
    int tile = blockIdx.x * 4 + w;

    float4 c0 = make_float4(0.f, 0.f, 0.f, 0.f), c1 = c0;
    {
        int pt = tile * 16 + l15;
        if (tile < numTiles && pt < N) {
            const float4* s = (const float4*)(feats + (size_t)pt * CIN + quad * 8);
            c0 = s[0]; c1 = s[1];
        }
    }

    while (tile < numTiles) {
        // prefetch next tile
        int nt = tile + stride;
        float4 n0 = make_float4(0.f, 0.f, 0.f, 0.f), n1 = n0;
        {
            int npt = nt * 16 + l15;
            if (nt < numTiles && npt < N) {
                const float4* s = (const float4*)(feats + (size_t)npt * CIN + quad * 8);
                n0 = s[0]; n1 = s[1];
            }
        }
        // convert current B-frag (feats[pt][quad*8..+7] -> 8 bf16)
        union { short8 v; unsigned u[4]; } b;
        b.u[0] = pk2bf(c0.x, c0.y);
        b.u[1] = pk2bf(c0.z, c0.w);
        b.u[2] = pk2bf(c1.x, c1.y);
        b.u[3] = pk2bf(c1.z, c1.w);

        float4v acc[4];
        #pragma unroll
        for (int mt = 0; mt < 4; ++mt)
            acc[mt] = __builtin_amdgcn_mfma_f32_16x16x32_bf16(
                aw[mt], b.v, (float4v){0.f, 0.f, 0.f, 0.f}, 0, 0, 0);

        int pt = tile * 16 + l15;
        if (pt < N) {
            #pragma unroll
            for (int mt = 0; mt < 4; ++mt) {
                uint2 o;
                o.x = pk2bf(acc[mt][0], acc[mt][1]);
                o.y = pk2bf(acc[mt][2], acc[mt][3]);
                *(uint2*)(t_bf + (size_t)pt * COUT + mt * 16 + quad * 4) = o;
            }
        }
        // stats (padded lanes contribute exact zeros)
        #pragma unroll
        for (int mt = 0; mt < 4; ++mt)
            #pragma unroll
            for (int e = 0; e < 4; ++e) {
                float v = acc[mt][e];
                s1[mt * 4 + e] += v; sq[mt * 4 + e] += v * v;
            }
        c0 = n0; c1 = n1;
        tile = nt;
    }

    // reduce stats: butterfly over the 16 point-lanes, then LDS, then global
    #pragma unroll
    for (int m = 1; m <= 8; m <<= 1) {
        #pragma unroll
        for (int e = 0; e < 16; ++e) {
            s1[e] += __shfl_xor(s1[e], m);
            sq[e] += __shfl_xor(sq[e], m);
        }
    }
    if (l15 == 0) {
        #pragma unroll
        for (int e = 0; e < 16; ++e) {
            int ch = (e >> 2) * 16 + quad * 4 + (e & 3);
            atomicAdd(&red_s[ch], s1[e]);
            atomicAdd(&red_q[ch], sq[e]);
        }
    }
    __syncthreads();
    float* dst = red0 + (size_t)(blockIdx.x & 3) * 128;
    if (t < 64)       atomicAdd(&dst[t], red_s[t]);
    else if (t < 128) atomicAdd(&dst[t], red_q[t - 64]);
}

// BN finalize from 4-way-spread sum/sumsq (for BN0)
__global__ void fin0_kernel(const float* __restrict__ red, const float* __restrict__ g,
                            const float* __restrict__ b, float* __restrict__ scale,
                            float* __restrict__ shift, int cnt)
{
    int c = threadIdx.x;  // 64
    float s = 0.f, q = 0.f;
    #pragma unroll
    for (int i = 0; i < 4; ++i) { s += red[i * 128 + c]; q += red[i * 128 + 64 + c]; }
    float m = s / (float)cnt;
    float var = q / (float)cnt - m * m;
    float sc = g[c] / sqrtf(var + EPSF);
    scale[c] = sc;
    shift[c] = b[c] - m * sc;
}

// ---------------------------------------------------------------------------
// Bucket build: pooling cell = 2x2x4 = 16 voxels max -> fixed capacity 16.
// ---------------------------------------------------------------------------
__global__ void bucket_kernel(const int* __restrict__ pool_seg,
                              int* __restrict__ cnt, int* __restrict__ bucket, int N)
{
    int j = blockIdx.x * 256 + threadIdx.x;
    if (j < N) {
        int s = pool_seg[j];
        int pos = atomicAdd(&cnt[s], 1);
        bucket[(size_t)s * 16 + pos] = j;
    }
}

// ---------------------------------------------------------------------------
// Gather-only pool: thread = (segment, 4 channels).
// ---------------------------------------------------------------------------
__global__ __launch_bounds__(256) void pool_max_kernel(
    const unsigned short* __restrict__ t_bf,
    const int* __restrict__ cnt, const int* __restrict__ bucket,
    const float* __restrict__ scale0, const float* __restrict__ shift0,
    unsigned short* __restrict__ down_bf, int M)
{
    int id = blockIdx.x * 256 + threadIdx.x;
    int s = id >> 4, cg = id & 15;
    if (s >= M) return;
    int n = cnt[s];
    const int4* bk4 = (const int4*)(bucket + (size_t)s * 16);
    float4 mx = make_float4(-INFINITY, -INFINITY, -INFINITY, -INFINITY);
    float4 mn = make_float4( INFINITY,  INFINITY,  INFINITY,  INFINITY);
    #pragma unroll
    for (int ch = 0; ch < 4; ++ch) {
        if (ch * 4 >= n) break;
        int4 b4 = bk4[ch];
        #pragma unroll
        for (int e = 0; e < 4; ++e) {
            int p = ch * 4 + e;
            if (p < n) {
                int idx = (e == 0) ? b4.x : (e == 1) ? b4.y : (e == 2) ? b4.z : b4.w;
                ushort4 v = *(const ushort4*)(t_bf + (size_t)idx * COUT + cg * 4);
                float f0 = bf2f(v.x), f1 = bf2f(v.y), f2 = bf2f(v.z), f3 = bf2f(v.w);
                mx.x = fmaxf(mx.x, f0); mn.x = fminf(mn.x, f0);
                mx.y = fmaxf(mx.y, f1); mn.y = fminf(mn.y, f1);
                mx.z = fmaxf(mx.z, f2); mn.z = fminf(mn.z, f2);
                mx.w = fmaxf(mx.w, f3); mn.w = fminf(mn.w, f3);
            }
        }
    }
    int c0 = cg * 4;
    float4 sc = *(const float4*)(scale0 + c0);
    float4 sh = *(const float4*)(shift0 + c0);
    ushort4 o;
    o.x = f2bf(eluf(sc.x * (sc.x >= 0.f ? mx.x : mn.x) + sh.x));
    o.y = f2bf(eluf(sc.y * (sc.y >= 0.f ? mx.y : mn.y) + sh.y));
    o.z = f2bf(eluf(sc.z * (sc.z >= 0.f ? mx.z : mn.z) + sh.z));
    o.w = f2bf(eluf(sc.w * (sc.w >= 0.f ? mx.w : mn.w) + sh.w));
    *(ushort4*)(down_bf + (size_t)s * COUT + c0) = o;
}

// invert (k, pairlist) maps into nbrT[k][M] (transposed for coalesced conv reads)
__global__ void nbr_kernel(const int* __restrict__ conv_out, const int* __restrict__ conv_in,
                           int* __restrict__ nbrT, int L, int M)
{
    int k = blockIdx.y;
    int idx = blockIdx.x * 256 + threadIdx.x;
    if (idx < L) {
        int e = k * L + idx;
        int j = conv_out[e];
        if (j < M) nbrT[(size_t)k * M + j] = conv_in[e];
    }
}

// o1t = bf16( ELU(scale1*o1 + shift1) )  -- conv2's A-matrix. float4 vectorized.
__global__ void bn_elu_cvt_kernel(const float* __restrict__ o1,
                                  const float* __restrict__ scale,
                                  const float* __restrict__ shift,
                                  unsigned short* __restrict__ o1t, int n4)
{
    int i = blockIdx.x * 256 + threadIdx.x;
    if (i < n4) {
        float4 v = ((const float4*)o1)[i];
        int c0 = (i & 15) * 4;
        float4 sc = *(const float4*)(scale + c0);
        float4 sh = *(const float4*)(shift + c0);
        ushort4 o;
        o.x = f2bf(eluf(v.x * sc.x + sh.x));
        o.y = f2bf(eluf(v.y * sc.y + sh.y));
        o.z = f2bf(eluf(v.z * sc.z + sh.z));
        o.w = f2bf(eluf(v.w * sc.w + sh.w));
        ((ushort4*)o1t)[i] = o;
    }
}

// ---------------------------------------------------------------------------
// MFMA implicit-GEMM sparse conv. v3:
//  - Block = 256 rows x 64 cols, 512 threads (8 waves x 32 rows).
//  - LDS exactly 80 KB (A dbuf 64K + W dbuf 16K) -> 2 blocks/CU = 16 waves/CU.
//    BN-stat scratch aliased into W_lds after the k-loop.
//  - 1 barrier/k reg-prefetch pipeline + XOR swizzle (0 bank conflicts).
//  - XCD-chunked bijective blockIdx swizzle: each XCD's gather working set
//    (~M/8 rows + halo ~ 3.5 MB) fits its private 4 MB L2 -> gather served
//    from L2 instead of L3; halves W staging traffic vs 128-row tiles.
// ---------------------------------------------------------------------------
__global__ __launch_bounds__(512) void conv_mfma_kernel(
    const unsigned short* __restrict__ in, const unsigned short* __restrict__ Wt,
    const int* __restrict__ nbrT, int M,
    float* __restrict__ out, float* __restrict__ red)
{
    __shared__ __align__(16) unsigned short A_lds[2][256 * 64];  // 64 KB
    __shared__ __align__(16) unsigned short W_lds[2][64 * 64];   // 16 KB
    int t = threadIdx.x;

    // XCD-chunked bijective remap (m204): blocks with equal (bid&7) are
    // co-resident on one XCD and get a contiguous range of output tiles.
    int nwg = gridDim.x;
    int q = nwg >> 3, r = nwg & 7;
    int xcd = blockIdx.x & 7, pos = blockIdx.x >> 3;
    int sb = (xcd < r ? xcd * (q + 1) : r * (q + 1) + (xcd - r) * q) + pos;
    int base = sb * 256;

    int w = t >> 6, lane = t & 63, l15 = lane & 15, quad = lane >> 4;

    float4v acc[2][4];
    #pragma unroll
    for (int s = 0; s < 2; ++s)
        #pragma unroll
        for (int n = 0; n < 4; ++n)
            acc[s][n] = (float4v){0.f, 0.f, 0.f, 0.f};

    int ar = t >> 1, ah = t & 1;   // A staging: row (0..255), 64B-half
    int gj = base + ar;
    int arx = ar & 7;              // A row swizzle key
    int wc = t >> 3, wq = t & 7;   // W staging: row (0..63), 16B-slot
    int wcx = wc & 7;              // W row swizzle key

    const u16x8 z8 = (u16x8){0, 0, 0, 0, 0, 0, 0, 0};

    // ---- prologue: stage k=0 into buf0, prefetch idx for k=1 ----
    {
        int idx0 = (gj < M) ? nbrT[gj] : -1;
        u16x8 a0 = z8, a1 = z8, a2 = z8, a3 = z8;
        if (idx0 >= 0) {
            const u16x8* src = (const u16x8*)(in + (size_t)idx0 * COUT + 32 * ah);
            a0 = src[0]; a1 = src[1]; a2 = src[2]; a3 = src[3];
        }
        u16x8 w0 = *(const u16x8*)(Wt + (size_t)wc * COUT + wq * 8);

        unsigned short* Ab = A_lds[0];
        *(u16x8*)(Ab + ar * 64 + ((ah * 4 + 0) ^ arx) * 8) = a0;
        *(u16x8*)(Ab + ar * 64 + ((ah * 4 + 1) ^ arx) * 8) = a1;
        *(u16x8*)(Ab + ar * 64 + ((ah * 4 + 2) ^ arx) * 8) = a2;
        *(u16x8*)(Ab + ar * 64 + ((ah * 4 + 3) ^ arx) * 8) = a3;
        *(u16x8*)(W_lds[0] + wc * 64 + ((wq ^ wcx) * 8)) = w0;
    }
    int idxN = (gj < M) ? nbrT[(size_t)M + gj] : -1;  // k=1
    __syncthreads();

    for (int k = 0; k < KVOL; ++k) {
        int cur = k & 1;
        bool pf = (k + 1 < KVOL);

        // ---- issue prefetch for k+1 (regs) ----
        u16x8 na0 = z8, na1 = z8, na2 = z8, na3 = z8, nw0 = z8;
        if (pf) {
            if (idxN >= 0) {
                const u16x8* src = (const u16x8*)(in + (size_t)idxN * COUT + 32 * ah);
                na0 = src[0]; na1 = src[1]; na2 = src[2]; na3 = src[3];
            }
            nw0 = *(const u16x8*)(Wt + (size_t)(k + 1) * (COUT * COUT) + (size_t)wc * COUT + wq * 8);
            idxN = (k + 2 < KVOL && gj < M) ? nbrT[(size_t)(k + 2) * M + gj] : -1;
        }

        // ---- compute on buf[cur] ----
        const unsigned short* Ab = A_lds[cur];
        const unsigned short* Wb = W_lds[cur];
        #pragma unroll
        for (int kk = 0; kk < 64; kk += 32) {
            int slb = quad + (kk >> 3);  // 16B slot index 0..7
            int r0 = 32 * w + l15;
            short8 a0 = *(const short8*)(Ab + r0 * 64 + ((slb ^ (r0 & 7)) * 8));
            int r1 = r0 + 16;
            short8 a1 = *(const short8*)(Ab + r1 * 64 + ((slb ^ (r1 & 7)) * 8));
            #pragma unroll
            for (int n = 0; n < 4; ++n) {
                int rb = 16 * n + l15;
                short8 b = *(const short8*)(Wb + rb * 64 + ((slb ^ (rb & 7)) * 8));
                acc[0][n] = __builtin_amdgcn_mfma_f32_16x16x32_bf16(a0, b, acc[0][n], 0, 0, 0);
                acc[1][n] = __builtin_amdgcn_mfma_f32_16x16x32_bf16(a1, b, acc[1][n], 0, 0, 0);
            }
        }

        // ---- drain prefetch into back buffer ----
        if (pf) {
            unsigned short* An = A_lds[cur ^ 1];
            *(u16x8*)(An + ar * 64 + ((ah * 4 + 0) ^ arx) * 8) = na0;
            *(u16x8*)(An + ar * 64 + ((ah * 4 + 1) ^ arx) * 8) = na1;
            *(u16x8*)(An + ar * 64 + ((ah * 4 + 2) ^ arx) * 8) = na2;
            *(u16x8*)(An + ar * 64 + ((ah * 4 + 3) ^ arx) * 8) = na3;
            *(u16x8*)(W_lds[cur ^ 1] + wc * 64 + ((wq ^ wcx) * 8)) = nw0;
        }
        __syncthreads();
    }

    // stores (C/D layout: col=lane&15, row=quad*4+reg)
    #pragma unroll
    for (int s = 0; s < 2; ++s) {
        int row = base + 32 * w + 16 * s + quad * 4;
        #pragma unroll
        for (int n = 0; n < 4; ++n) {
            int c = 16 * n + l15;
            #pragma unroll
            for (int e = 0; e < 4; ++e)
                if (row + e < M) out[(size_t)(row + e) * COUT + c] = acc[s][n][e];
        }
    }

    // fused BN stats (rows >= M are exact zeros). Scratch aliased into W_lds
    // (dead after the final k-loop barrier).
    float* red_s = (float*)(W_lds[0]);
    float* red_q = red_s + 64;
    if (t < 128) red_s[t] = 0.f;
    __syncthreads();
    #pragma unroll
    for (int n = 0; n < 4; ++n) {
        float s1 = 0.f, sq = 0.f;
        #pragma unroll
        for (int s = 0; s < 2; ++s)
            #pragma unroll
            for (int e = 0; e < 4; ++e) { float v = acc[s][n][e]; s1 += v; sq += v * v; }
        s1 += __shfl_xor(s1, 16); sq += __shfl_xor(sq, 16);
        s1 += __shfl_xor(s1, 32); sq += __shfl_xor(sq, 32);
        if (quad == 0) {
            atomicAdd(&red_s[16 * n + l15], s1);
            atomicAdd(&red_q[16 * n + l15], sq);
        }
    }
    __syncthreads();
    if (t < 64)       atomicAdd(&red[t], red_s[t]);
    else if (t < 128) atomicAdd(&red[t], red_q[t - 64]);
}

// BN finalize from sum/sumsq: scale = g/sqrt(var+eps), shift = b - mean*scale
__global__ void finC_kernel(const float* __restrict__ red, const float* __restrict__ g,
                            const float* __restrict__ b, float* __restrict__ scale,
                            float* __restrict__ shift, int M)
{
    int c = threadIdx.x;  // 64
    float m = red[c] / (float)M;
    float var = red[64 + c] / (float)M - m * m;
    float sc = g[c] / sqrtf(var + EPSF);
    scale[c] = sc;
    shift[c] = b[c] - m * sc;
}

// out = elu( elu(scale2*raw + shift2) + down )  -- float4 vectorized
__global__ void final_kernel(float* __restrict__ out, const unsigned short* __restrict__ down_bf,
                             const float* __restrict__ scale2, const float* __restrict__ shift2,
                             int n4)
{
    int i = blockIdx.x * 256 + threadIdx.x;
    if (i < n4) {
        float4 v = ((const float4*)out)[i];
        ushort4 d = ((const ushort4*)down_bf)[i];
        int c0 = (i & 15) * 4;
        float4 sc = *(const float4*)(scale2 + c0);
        float4 sh = *(const float4*)(shift2 + c0);
        v.x = eluf(eluf(v.x * sc.x + sh.x) + bf2f(d.x));
        v.y = eluf(eluf(v.y * sc.y + sh.y) + bf2f(d.y));
        v.z = eluf(eluf(v.z * sc.z + sh.z) + bf2f(d.z));
        v.w = eluf(eluf(v.w * sc.w + sh.w) + bf2f(d.w));
        ((float4*)out)[i] = v;
    }
}

extern "C" void kernel_launch(void* const* d_in, const int* in_sizes, int n_in,
                              void* d_out, int out_size, void* d_ws, size_t ws_size,
                              hipStream_t stream)
{
    (void)n_in; (void)ws_size;
    const float* feats    = (const float*)d_in[0];
    const float* Wd       = (const float*)d_in[1];
    const float* g0       = (const float*)d_in[2];
    const float* b0       = (const float*)d_in[3];
    const float* W1       = (const float*)d_in[4];
    const float* g1       = (const float*)d_in[5];
    const float* b1       = (const float*)d_in[6];
    const float* W2       = (const float*)d_in[7];
    const float* g2       = (const float*)d_in[8];
    const float* b2       = (const float*)d_in[9];
    const int*   pool_seg = (const int*)d_in[10];
    const int*   conv_in  = (const int*)d_in[11];
    const int*   conv_out = (const int*)d_in[12];

    int N = in_sizes[0] / CIN;
    int M = out_size / COUT;
    int L = in_sizes[11] / KVOL;

    char* ws = (char*)d_ws;
    size_t off = 0;
    auto alloc = [&](size_t bytes) -> void* {
        void* p = ws + off;
        off = (off + bytes + 255) & ~(size_t)255;
        return p;
    };
    float*          o1      = (float*)alloc((size_t)M * COUT * 4);
    unsigned short* down_bf = (unsigned short*)alloc((size_t)M * COUT * 2);
    unsigned short* o1t     = (unsigned short*)alloc((size_t)M * COUT * 2);
    unsigned short* t_bf    = (unsigned short*)alloc((size_t)N * COUT * 2);
    int*            nbrT    = (int*)alloc((size_t)KVOL * M * 4);
    unsigned short* Wt1     = (unsigned short*)alloc((size_t)KVOL * COUT * COUT * 2);
    unsigned short* Wt2     = (unsigned short*)alloc((size_t)KVOL * COUT * COUT * 2);
    unsigned short* Wdt     = (unsigned short*)alloc((size_t)CIN * COUT * 2);
    int*            cnt     = (int*)alloc((size_t)M * 4);
    int*            bucket  = (int*)alloc((size_t)M * 16 * 4);
    float* red  = (float*)alloc((size_t)768 * 4);
    float* red0 = red, *red1 = red + 512, *red2 = red + 640;
    float* sreg = (float*)alloc((size_t)6 * 64 * 4);
    float* scale0 = sreg, *shift0 = sreg + 64;
    float* scale1 = sreg + 128, *shift1 = sreg + 192;
    float* scale2 = sreg + 256, *shift2 = sreg + 320;

    hipMemsetAsync(nbrT, 0xFF, (size_t)KVOL * M * 4, stream);  // -1 = missing neighbor
    hipMemsetAsync(cnt, 0, (size_t)M * 4, stream);             // bucket counters
    hipMemsetAsync(red, 0, (size_t)768 * 4, stream);           // stat accumulators

    cvt_w_kernel<<<55, 256, 0, stream>>>(W1, W2, Wd, Wt1, Wt2, Wdt);
    gemm_t_kernel<<<1024, 256, 0, stream>>>(feats, Wdt, N, t_bf, red0);
    fin0_kernel<<<1, 64, 0, stream>>>(red0, g0, b0, scale0, shift0, N);
    bucket_kernel<<<(N + 255) / 256, 256, 0, stream>>>(pool_seg, cnt, bucket, N);
    pool_max_kernel<<<(M * 16 + 255) / 256, 256, 0, stream>>>(
        t_bf, cnt, bucket, scale0, shift0, down_bf, M);
    dim3 gn((L + 255) / 256, KVOL);
    nbr_kernel<<<gn, 256, 0, stream>>>(conv_out, conv_in, nbrT, L, M);

    int cblocks = (M + 255) / 256;
    conv_mfma_kernel<<<cblocks, 512, 0, stream>>>(down_bf, Wt1, nbrT, M, o1, red1);
    finC_kernel<<<1, 64, 0, stream>>>(red1, g1, b1, scale1, shift1, M);
    int n4 = (M * COUT) / 4;
    bn_elu_cvt_kernel<<<(n4 + 255) / 256, 256, 0, stream>>>(o1, scale1, shift1, o1t, n4);
    conv_mfma_kernel<<<cblocks, 512, 0, stream>>>(o1t, Wt2, nbrT, M, (float*)d_out, red2);
    finC_kernel<<<1, 64, 0, stream>>>(red2, g2, b2, scale2, shift2, M);
    final_kernel<<<(n4 + 255) / 256, 256, 0, stream>>>(
        (float*)d_out, down_bf, scale2, shift2, n4);
}